// Round 1
// baseline (804.166 us; speedup 1.0000x reference)
//
#include <hip/hip_runtime.h>

#define N_NODES 50000
#define N_EDGES 800000
#define NF 128
#define N_GRAPHS 512

// ---------------- GEMM: C[M,128] = act(A)[M,128] @ W[128,128] ----------------
// Tile: 64 rows x 128 cols per 256-thread block, K-tiled by 32.
// Thread (rg,cg) computes rows rg*4..+3, cols cg*8..+7 (32 accumulators).
// LDS: sW 16KB + sA ~9KB -> high occupancy. sA padded to 36 floats/row (2-way max).
template<bool RELU>
__global__ __launch_bounds__(256) void gemm128(const float* __restrict__ A,
                                               const float* __restrict__ W,
                                               float* __restrict__ C, int M) {
  __shared__ float sW[32][128];
  __shared__ float sA[64][36];
  const int tid = threadIdx.x;
  const int row0 = blockIdx.x * 64;
  const int rg = tid >> 4;   // 0..15 -> 4 rows each
  const int cg = tid & 15;   // 0..15 -> 8 cols each

  float4 acc[4][2];
#pragma unroll
  for (int i = 0; i < 4; ++i) {
    acc[i][0] = float4{0.f, 0.f, 0.f, 0.f};
    acc[i][1] = float4{0.f, 0.f, 0.f, 0.f};
  }

  for (int kt = 0; kt < 128; kt += 32) {
    // stage W k-tile: 32x128 floats = 1024 float4, 4 per thread (coalesced)
#pragma unroll
    for (int i = 0; i < 4; ++i) {
      int idx = i * 256 + tid;
      int r = idx >> 5, c4 = idx & 31;
      ((float4*)&sW[r][0])[c4] = ((const float4*)W)[(kt + r) * 32 + c4];
    }
    // stage A tile: 64x32 floats = 512 float4, 2 per thread
#pragma unroll
    for (int i = 0; i < 2; ++i) {
      int idx = i * 256 + tid;
      int r = idx >> 3, c4 = idx & 7;
      int gr = row0 + r;
      float4 v = float4{0.f, 0.f, 0.f, 0.f};
      if (gr < M) v = ((const float4*)A)[gr * 32 + (kt >> 2) + c4];
      if (RELU) {
        v.x = fmaxf(v.x, 0.f); v.y = fmaxf(v.y, 0.f);
        v.z = fmaxf(v.z, 0.f); v.w = fmaxf(v.w, 0.f);
      }
      *(float4*)&sA[r][c4 * 4] = v;
    }
    __syncthreads();

#pragma unroll
    for (int k = 0; k < 32; k += 4) {
      float4 a0 = *(const float4*)&sA[rg * 4 + 0][k];
      float4 a1 = *(const float4*)&sA[rg * 4 + 1][k];
      float4 a2 = *(const float4*)&sA[rg * 4 + 2][k];
      float4 a3 = *(const float4*)&sA[rg * 4 + 3][k];
      const float* ap0 = (const float*)&a0;
      const float* ap1 = (const float*)&a1;
      const float* ap2 = (const float*)&a2;
      const float* ap3 = (const float*)&a3;
#pragma unroll
      for (int kk = 0; kk < 4; ++kk) {
        float4 w0 = *(const float4*)&sW[k + kk][cg * 8];
        float4 w1 = *(const float4*)&sW[k + kk][cg * 8 + 4];
        float a0k = ap0[kk], a1k = ap1[kk], a2k = ap2[kk], a3k = ap3[kk];
#define FMA_ROW(I, AK)                                                         \
        acc[I][0].x += AK * w0.x; acc[I][0].y += AK * w0.y;                    \
        acc[I][0].z += AK * w0.z; acc[I][0].w += AK * w0.w;                    \
        acc[I][1].x += AK * w1.x; acc[I][1].y += AK * w1.y;                    \
        acc[I][1].z += AK * w1.z; acc[I][1].w += AK * w1.w;
        FMA_ROW(0, a0k)
        FMA_ROW(1, a1k)
        FMA_ROW(2, a2k)
        FMA_ROW(3, a3k)
#undef FMA_ROW
      }
    }
    __syncthreads();
  }

#pragma unroll
  for (int i = 0; i < 4; ++i) {
    int gr = row0 + rg * 4 + i;
    if (gr < M) {
      ((float4*)C)[gr * 32 + cg * 2 + 0] = acc[i][0];
      ((float4*)C)[gr * 32 + cg * 2 + 1] = acc[i][1];
    }
  }
}

// ------------- scatter-add: out[dst[e]][f] += h[src[e]][f] -------------------
// one thread per (edge, feature): loads coalesced (512B/edge), atomics
// coalesced (64 consecutive f32 per wave instruction).
__global__ __launch_bounds__(256) void scatter_add(const float* __restrict__ h,
                                                   const int* __restrict__ src,
                                                   const int* __restrict__ dst,
                                                   float* __restrict__ out) {
  unsigned gid = blockIdx.x * 256u + threadIdx.x;
  unsigned e = gid >> 7;
  unsigned f = gid & 127u;
  if (e < N_EDGES) {
    int s = src[e];
    int d = dst[e];
    unsafeAtomicAdd(&out[(size_t)d * NF + f], h[(size_t)s * NF + f]);
  }
}

// ------------- fused mean-pool + FC + sigmoid --------------------------------
// batch is sorted: block g binary-searches its node range, sums rows directly
// (no atomics, no counts buffer), then 128-thread reduction for the dot.
__global__ __launch_bounds__(128) void pool_fc(const float* __restrict__ a,
                                               const int* __restrict__ batch,
                                               const float* __restrict__ Wfc,
                                               float* __restrict__ out) {
  __shared__ float red[2];
  int g = blockIdx.x;
  int f = threadIdx.x;

  int lo = 0, hi = N_NODES;
  while (lo < hi) { int mid = (lo + hi) >> 1; if (batch[mid] < g) lo = mid + 1; else hi = mid; }
  int s0 = lo;
  lo = 0; hi = N_NODES;
  while (lo < hi) { int mid = (lo + hi) >> 1; if (batch[mid] < g + 1) lo = mid + 1; else hi = mid; }
  int s1 = lo;

  float acc = 0.f;
  for (int n = s0; n < s1; ++n) acc += a[(size_t)n * NF + f];

  float cnt = fmaxf((float)(s1 - s0), 1.0f);
  float v = (acc / cnt) * Wfc[f];

#pragma unroll
  for (int off = 32; off > 0; off >>= 1) v += __shfl_down(v, off, 64);
  if ((f & 63) == 0) red[f >> 6] = v;
  __syncthreads();
  if (f == 0) {
    float z = red[0] + red[1];
    out[g] = 1.0f / (1.0f + expf(-z));
  }
}

extern "C" void kernel_launch(void* const* d_in, const int* in_sizes, int n_in,
                              void* d_out, int out_size, void* d_ws, size_t ws_size,
                              hipStream_t stream) {
  const float* x   = (const float*)d_in[0];
  const int*   ei  = (const int*)d_in[1];
  const int*   src = ei;               // edge_index[0]
  const int*   dst = ei + N_EDGES;     // edge_index[1]
  const int* batch = (const int*)d_in[2];
  const float* W1  = (const float*)d_in[3];
  const float* W2  = (const float*)d_in[4];
  const float* Wfc = (const float*)d_in[5];
  float* out = (float*)d_out;

  float* bufA = (float*)d_ws;                       // h (x@W1, then relu(a1)@W2)
  float* bufB = bufA + (size_t)N_NODES * NF;        // scatter accumulator
  const size_t nbytes = (size_t)N_NODES * NF * sizeof(float);

  const int gemm_grid = (N_NODES + 63) / 64;                 // 782
  const int scat_grid = (N_EDGES * NF) / 256;                // 400000

  hipMemsetAsync(bufB, 0, nbytes, stream);
  gemm128<false><<<gemm_grid, 256, 0, stream>>>(x, W1, bufA, N_NODES);
  scatter_add<<<scat_grid, 256, 0, stream>>>(bufA, src, dst, bufB);
  gemm128<true><<<gemm_grid, 256, 0, stream>>>(bufB, W2, bufA, N_NODES);
  hipMemsetAsync(bufB, 0, nbytes, stream);
  scatter_add<<<scat_grid, 256, 0, stream>>>(bufA, src, dst, bufB);
  pool_fc<<<N_GRAPHS, 128, 0, stream>>>(bufB, batch, Wfc, out);
}

// Round 2
// 382.850 us; speedup vs baseline: 2.1005x; 2.1005x over previous
//
#include <hip/hip_runtime.h>

#define N_NODES 50000
#define N_EDGES 800000
#define NF 128
#define N_GRAPHS 512

// ---------------- GEMM: C[M,128] = act(A)[M,128] @ W[128,128] ----------------
template<bool RELU>
__global__ __launch_bounds__(256) void gemm128(const float* __restrict__ A,
                                               const float* __restrict__ W,
                                               float* __restrict__ C, int M) {
  __shared__ float sW[32][128];
  __shared__ float sA[64][36];
  const int tid = threadIdx.x;
  const int row0 = blockIdx.x * 64;
  const int rg = tid >> 4;   // 0..15 -> 4 rows each
  const int cg = tid & 15;   // 0..15 -> 8 cols each

  float4 acc[4][2];
#pragma unroll
  for (int i = 0; i < 4; ++i) {
    acc[i][0] = float4{0.f, 0.f, 0.f, 0.f};
    acc[i][1] = float4{0.f, 0.f, 0.f, 0.f};
  }

  for (int kt = 0; kt < 128; kt += 32) {
#pragma unroll
    for (int i = 0; i < 4; ++i) {
      int idx = i * 256 + tid;
      int r = idx >> 5, c4 = idx & 31;
      ((float4*)&sW[r][0])[c4] = ((const float4*)W)[(kt + r) * 32 + c4];
    }
#pragma unroll
    for (int i = 0; i < 2; ++i) {
      int idx = i * 256 + tid;
      int r = idx >> 3, c4 = idx & 7;
      int gr = row0 + r;
      float4 v = float4{0.f, 0.f, 0.f, 0.f};
      if (gr < M) v = ((const float4*)A)[gr * 32 + (kt >> 2) + c4];
      if (RELU) {
        v.x = fmaxf(v.x, 0.f); v.y = fmaxf(v.y, 0.f);
        v.z = fmaxf(v.z, 0.f); v.w = fmaxf(v.w, 0.f);
      }
      *(float4*)&sA[r][c4 * 4] = v;
    }
    __syncthreads();

#pragma unroll
    for (int k = 0; k < 32; k += 4) {
      float4 a0 = *(const float4*)&sA[rg * 4 + 0][k];
      float4 a1 = *(const float4*)&sA[rg * 4 + 1][k];
      float4 a2 = *(const float4*)&sA[rg * 4 + 2][k];
      float4 a3 = *(const float4*)&sA[rg * 4 + 3][k];
      const float* ap0 = (const float*)&a0;
      const float* ap1 = (const float*)&a1;
      const float* ap2 = (const float*)&a2;
      const float* ap3 = (const float*)&a3;
#pragma unroll
      for (int kk = 0; kk < 4; ++kk) {
        float4 w0 = *(const float4*)&sW[k + kk][cg * 8];
        float4 w1 = *(const float4*)&sW[k + kk][cg * 8 + 4];
        float a0k = ap0[kk], a1k = ap1[kk], a2k = ap2[kk], a3k = ap3[kk];
#define FMA_ROW(I, AK)                                                         \
        acc[I][0].x += AK * w0.x; acc[I][0].y += AK * w0.y;                    \
        acc[I][0].z += AK * w0.z; acc[I][0].w += AK * w0.w;                    \
        acc[I][1].x += AK * w1.x; acc[I][1].y += AK * w1.y;                    \
        acc[I][1].z += AK * w1.z; acc[I][1].w += AK * w1.w;
        FMA_ROW(0, a0k)
        FMA_ROW(1, a1k)
        FMA_ROW(2, a2k)
        FMA_ROW(3, a3k)
#undef FMA_ROW
      }
    }
    __syncthreads();
  }

#pragma unroll
  for (int i = 0; i < 4; ++i) {
    int gr = row0 + rg * 4 + i;
    if (gr < M) {
      ((float4*)C)[gr * 32 + cg * 2 + 0] = acc[i][0];
      ((float4*)C)[gr * 32 + cg * 2 + 1] = acc[i][1];
    }
  }
}

// ---------------- CSR build: dst -> list of src ------------------------------
__global__ __launch_bounds__(256) void hist_kernel(const int* __restrict__ dst,
                                                   int* __restrict__ deg) {
  unsigned e = blockIdx.x * 256u + threadIdx.x;
  if (e < N_EDGES) atomicAdd(&deg[dst[e]], 1);
}

// single-block exclusive scan of deg[0..N_NODES) -> rowptr[0..N_NODES]
__global__ __launch_bounds__(1024) void scan_kernel(const int* __restrict__ deg,
                                                    int* __restrict__ rowptr) {
  __shared__ int tmp[1024];
  __shared__ int carry_s;
  const int tid = threadIdx.x;
  if (tid == 0) { rowptr[0] = 0; carry_s = 0; }
  __syncthreads();
  for (int base = 0; base < N_NODES; base += 1024) {
    int i = base + tid;
    int v = (i < N_NODES) ? deg[i] : 0;
    tmp[tid] = v;
    __syncthreads();
#pragma unroll
    for (int off = 1; off < 1024; off <<= 1) {
      int t = (tid >= off) ? tmp[tid - off] : 0;
      __syncthreads();
      tmp[tid] += t;
      __syncthreads();
    }
    int inc = tmp[tid];
    int c = carry_s;
    if (i < N_NODES) rowptr[i + 1] = c + inc;
    __syncthreads();
    if (tid == 1023) carry_s = c + inc;
    __syncthreads();
  }
}

__global__ __launch_bounds__(256) void fill_kernel(const int* __restrict__ src,
                                                   const int* __restrict__ dst,
                                                   int* __restrict__ cursor,
                                                   int* __restrict__ col) {
  unsigned e = blockIdx.x * 256u + threadIdx.x;
  if (e < N_EDGES) {
    int d = dst[e];
    int pos = atomicAdd(&cursor[d], 1);
    col[pos] = src[e];
  }
}

// ------------- gather aggregation: out[n][:] = sum_{j in CSR(n)} h[col[j]][:]
// 32 threads per node, float4 per thread (feats q*4..q*4+3).
__global__ __launch_bounds__(256) void gather_agg(const float* __restrict__ h,
                                                  const int* __restrict__ rowptr,
                                                  const int* __restrict__ col,
                                                  float* __restrict__ out) {
  unsigned gid = blockIdx.x * 256u + threadIdx.x;
  unsigned n = gid >> 5;
  unsigned q = gid & 31u;
  if (n >= N_NODES) return;
  int j0 = rowptr[n], j1 = rowptr[n + 1];
  float4 acc = float4{0.f, 0.f, 0.f, 0.f};
  int j = j0;
  for (; j + 2 <= j1; j += 2) {
    int s0 = col[j], s1 = col[j + 1];
    float4 v0 = ((const float4*)h)[(size_t)s0 * 32 + q];
    float4 v1 = ((const float4*)h)[(size_t)s1 * 32 + q];
    acc.x += v0.x + v1.x; acc.y += v0.y + v1.y;
    acc.z += v0.z + v1.z; acc.w += v0.w + v1.w;
  }
  if (j < j1) {
    int s0 = col[j];
    float4 v0 = ((const float4*)h)[(size_t)s0 * 32 + q];
    acc.x += v0.x; acc.y += v0.y; acc.z += v0.z; acc.w += v0.w;
  }
  ((float4*)out)[(size_t)n * 32 + q] = acc;
}

// ------------- fused mean-pool + FC + sigmoid --------------------------------
__global__ __launch_bounds__(128) void pool_fc(const float* __restrict__ a,
                                               const int* __restrict__ batch,
                                               const float* __restrict__ Wfc,
                                               float* __restrict__ out) {
  __shared__ float red[2];
  int g = blockIdx.x;
  int f = threadIdx.x;

  int lo = 0, hi = N_NODES;
  while (lo < hi) { int mid = (lo + hi) >> 1; if (batch[mid] < g) lo = mid + 1; else hi = mid; }
  int s0 = lo;
  lo = 0; hi = N_NODES;
  while (lo < hi) { int mid = (lo + hi) >> 1; if (batch[mid] < g + 1) lo = mid + 1; else hi = mid; }
  int s1 = lo;

  float acc = 0.f;
  for (int n = s0; n < s1; ++n) acc += a[(size_t)n * NF + f];

  float cnt = fmaxf((float)(s1 - s0), 1.0f);
  float v = (acc / cnt) * Wfc[f];

#pragma unroll
  for (int off = 32; off > 0; off >>= 1) v += __shfl_down(v, off, 64);
  if ((f & 63) == 0) red[f >> 6] = v;
  __syncthreads();
  if (f == 0) {
    float z = red[0] + red[1];
    out[g] = 1.0f / (1.0f + expf(-z));
  }
}

extern "C" void kernel_launch(void* const* d_in, const int* in_sizes, int n_in,
                              void* d_out, int out_size, void* d_ws, size_t ws_size,
                              hipStream_t stream) {
  const float* x   = (const float*)d_in[0];
  const int*   ei  = (const int*)d_in[1];
  const int*   src = ei;               // edge_index[0]
  const int*   dst = ei + N_EDGES;     // edge_index[1]
  const int* batch = (const int*)d_in[2];
  const float* W1  = (const float*)d_in[3];
  const float* W2  = (const float*)d_in[4];
  const float* Wfc = (const float*)d_in[5];
  float* out = (float*)d_out;

  float* bufA = (float*)d_ws;                         // 6.4M floats
  float* bufB = bufA + (size_t)N_NODES * NF;          // 6.4M floats
  int* deg    = (int*)(bufB + (size_t)N_NODES * NF);  // 50000
  int* rowptr = deg + N_NODES;                        // 50001
  int* cursor = rowptr + N_NODES + 1;                 // 50000
  int* col    = cursor + N_NODES;                     // 800000

  const int gemm_grid = (N_NODES + 63) / 64;            // 782
  const int edge_grid = (N_EDGES + 255) / 256;          // 3125
  const int agg_grid  = (N_NODES * 32 + 255) / 256;     // 6250

  // --- build CSR (dst -> srcs), reused by both convs ---
  hipMemsetAsync(deg, 0, N_NODES * sizeof(int), stream);
  hist_kernel<<<edge_grid, 256, 0, stream>>>(dst, deg);
  scan_kernel<<<1, 1024, 0, stream>>>(deg, rowptr);
  hipMemcpyAsync(cursor, rowptr, N_NODES * sizeof(int),
                 hipMemcpyDeviceToDevice, stream);
  fill_kernel<<<edge_grid, 256, 0, stream>>>(src, dst, cursor, col);

  // --- conv1: h = x@W1 ; aggregate ; (relu fused into next gemm's load) ---
  gemm128<false><<<gemm_grid, 256, 0, stream>>>(x, W1, bufA, N_NODES);
  gather_agg<<<agg_grid, 256, 0, stream>>>(bufA, rowptr, col, bufB);

  // --- conv2: h = relu(bufB)@W2 ; aggregate ---
  gemm128<true><<<gemm_grid, 256, 0, stream>>>(bufB, W2, bufA, N_NODES);
  gather_agg<<<agg_grid, 256, 0, stream>>>(bufA, rowptr, col, bufB);

  // --- pool + fc + sigmoid ---
  pool_fc<<<N_GRAPHS, 128, 0, stream>>>(bufB, batch, Wfc, out);
}

// Round 3
// 303.358 us; speedup vs baseline: 2.6509x; 1.2620x over previous
//
#include <hip/hip_runtime.h>

#define N_NODES 50000
#define N_EDGES 800000
#define NF 128
#define N_GRAPHS 512
#define SCAN_BLOCKS 196   // ceil(50000/256)

// ---------------- GEMM: C[M,128] = act(A)[M,128] @ W[128,128] ----------------
template<bool RELU>
__global__ __launch_bounds__(256) void gemm128(const float* __restrict__ A,
                                               const float* __restrict__ W,
                                               float* __restrict__ C, int M) {
  __shared__ float sW[32][128];
  __shared__ float sA[64][36];
  const int tid = threadIdx.x;
  const int row0 = blockIdx.x * 64;
  const int rg = tid >> 4;   // 0..15 -> 4 rows each
  const int cg = tid & 15;   // 0..15 -> 8 cols each

  float4 acc[4][2];
#pragma unroll
  for (int i = 0; i < 4; ++i) {
    acc[i][0] = float4{0.f, 0.f, 0.f, 0.f};
    acc[i][1] = float4{0.f, 0.f, 0.f, 0.f};
  }

  for (int kt = 0; kt < 128; kt += 32) {
#pragma unroll
    for (int i = 0; i < 4; ++i) {
      int idx = i * 256 + tid;
      int r = idx >> 5, c4 = idx & 31;
      ((float4*)&sW[r][0])[c4] = ((const float4*)W)[(kt + r) * 32 + c4];
    }
#pragma unroll
    for (int i = 0; i < 2; ++i) {
      int idx = i * 256 + tid;
      int r = idx >> 3, c4 = idx & 7;
      int gr = row0 + r;
      float4 v = float4{0.f, 0.f, 0.f, 0.f};
      if (gr < M) v = ((const float4*)A)[gr * 32 + (kt >> 2) + c4];
      if (RELU) {
        v.x = fmaxf(v.x, 0.f); v.y = fmaxf(v.y, 0.f);
        v.z = fmaxf(v.z, 0.f); v.w = fmaxf(v.w, 0.f);
      }
      *(float4*)&sA[r][c4 * 4] = v;
    }
    __syncthreads();

#pragma unroll
    for (int k = 0; k < 32; k += 4) {
      float4 a0 = *(const float4*)&sA[rg * 4 + 0][k];
      float4 a1 = *(const float4*)&sA[rg * 4 + 1][k];
      float4 a2 = *(const float4*)&sA[rg * 4 + 2][k];
      float4 a3 = *(const float4*)&sA[rg * 4 + 3][k];
      const float* ap0 = (const float*)&a0;
      const float* ap1 = (const float*)&a1;
      const float* ap2 = (const float*)&a2;
      const float* ap3 = (const float*)&a3;
#pragma unroll
      for (int kk = 0; kk < 4; ++kk) {
        float4 w0 = *(const float4*)&sW[k + kk][cg * 8];
        float4 w1 = *(const float4*)&sW[k + kk][cg * 8 + 4];
        float a0k = ap0[kk], a1k = ap1[kk], a2k = ap2[kk], a3k = ap3[kk];
#define FMA_ROW(I, AK)                                                         \
        acc[I][0].x += AK * w0.x; acc[I][0].y += AK * w0.y;                    \
        acc[I][0].z += AK * w0.z; acc[I][0].w += AK * w0.w;                    \
        acc[I][1].x += AK * w1.x; acc[I][1].y += AK * w1.y;                    \
        acc[I][1].z += AK * w1.z; acc[I][1].w += AK * w1.w;
        FMA_ROW(0, a0k)
        FMA_ROW(1, a1k)
        FMA_ROW(2, a2k)
        FMA_ROW(3, a3k)
#undef FMA_ROW
      }
    }
    __syncthreads();
  }

#pragma unroll
  for (int i = 0; i < 4; ++i) {
    int gr = row0 + rg * 4 + i;
    if (gr < M) {
      ((float4*)C)[gr * 32 + cg * 2 + 0] = acc[i][0];
      ((float4*)C)[gr * 32 + cg * 2 + 1] = acc[i][1];
    }
  }
}

// ---------------- CSR build: dst -> list of src ------------------------------
__global__ __launch_bounds__(256) void hist_kernel(const int* __restrict__ dst,
                                                   int* __restrict__ deg) {
  unsigned e = blockIdx.x * 256u + threadIdx.x;
  if (e < N_EDGES) atomicAdd(&deg[dst[e]], 1);
}

__device__ __forceinline__ int block_incl_scan_256(int v, int* warp_sums) {
  // inclusive scan of v across 256 threads (4 waves of 64)
  const int tid = threadIdx.x;
  const int lane = tid & 63;
  const int w = tid >> 6;
#pragma unroll
  for (int off = 1; off < 64; off <<= 1) {
    int t = __shfl_up(v, off, 64);
    if (lane >= off) v += t;
  }
  if (lane == 63) warp_sums[w] = v;
  __syncthreads();
  int ws = 0;
#pragma unroll
  for (int i = 0; i < 4; ++i) ws += (i < w) ? warp_sums[i] : 0;
  return v + ws;
}

// stage 1: per-block inclusive scan of deg -> rowptr[i+1] (no global offset),
//          block total -> blocksum[blockIdx]
__global__ __launch_bounds__(256) void scan_stage1(const int* __restrict__ deg,
                                                   int* __restrict__ rowptr,
                                                   int* __restrict__ blocksum) {
  __shared__ int warp_sums[4];
  int i = blockIdx.x * 256 + threadIdx.x;
  int v = (i < N_NODES) ? deg[i] : 0;
  int incl = block_incl_scan_256(v, warp_sums);
  if (i < N_NODES) rowptr[i + 1] = incl;
  if (threadIdx.x == 255) blocksum[blockIdx.x] = incl;
}

// stage 2: exclusive scan of blocksum[0..SCAN_BLOCKS) in place (1 block)
__global__ __launch_bounds__(256) void scan_stage2(int* __restrict__ blocksum) {
  __shared__ int warp_sums[4];
  int tid = threadIdx.x;
  int v = (tid < SCAN_BLOCKS) ? blocksum[tid] : 0;
  int incl = block_incl_scan_256(v, warp_sums);
  if (tid < SCAN_BLOCKS) blocksum[tid] = incl - v;  // exclusive
}

// stage 3: add block offsets; produce final rowptr and cursor copy
__global__ __launch_bounds__(256) void scan_stage3(int* __restrict__ rowptr,
                                                   const int* __restrict__ blocksum,
                                                   int* __restrict__ cursor) {
  int i = blockIdx.x * 256 + threadIdx.x;
  if (i < N_NODES) {
    int r = rowptr[i + 1] + blocksum[blockIdx.x];
    rowptr[i + 1] = r;
    cursor[i + 1] = r;
  }
  if (i == 0) { rowptr[0] = 0; cursor[0] = 0; }
}

__global__ __launch_bounds__(256) void fill_kernel(const int* __restrict__ src,
                                                   const int* __restrict__ dst,
                                                   int* __restrict__ cursor,
                                                   int* __restrict__ col) {
  unsigned e = blockIdx.x * 256u + threadIdx.x;
  if (e < N_EDGES) {
    int d = dst[e];
    int pos = atomicAdd(&cursor[d], 1);
    col[pos] = src[e];
  }
}

// ------------- gather aggregation: out[n][:] = sum_{j in CSR(n)} h[col[j]][:]
__global__ __launch_bounds__(256) void gather_agg(const float* __restrict__ h,
                                                  const int* __restrict__ rowptr,
                                                  const int* __restrict__ col,
                                                  float* __restrict__ out) {
  unsigned gid = blockIdx.x * 256u + threadIdx.x;
  unsigned n = gid >> 5;
  unsigned q = gid & 31u;
  if (n >= N_NODES) return;
  int j0 = rowptr[n], j1 = rowptr[n + 1];
  float4 acc = float4{0.f, 0.f, 0.f, 0.f};
  int j = j0;
  for (; j + 2 <= j1; j += 2) {
    int s0 = col[j], s1 = col[j + 1];
    float4 v0 = ((const float4*)h)[(size_t)s0 * 32 + q];
    float4 v1 = ((const float4*)h)[(size_t)s1 * 32 + q];
    acc.x += v0.x + v1.x; acc.y += v0.y + v1.y;
    acc.z += v0.z + v1.z; acc.w += v0.w + v1.w;
  }
  if (j < j1) {
    int s0 = col[j];
    float4 v0 = ((const float4*)h)[(size_t)s0 * 32 + q];
    acc.x += v0.x; acc.y += v0.y; acc.z += v0.z; acc.w += v0.w;
  }
  ((float4*)out)[(size_t)n * 32 + q] = acc;
}

// ------------- fused mean-pool + FC + sigmoid --------------------------------
__global__ __launch_bounds__(128) void pool_fc(const float* __restrict__ a,
                                               const int* __restrict__ batch,
                                               const float* __restrict__ Wfc,
                                               float* __restrict__ out) {
  __shared__ float red[2];
  int g = blockIdx.x;
  int f = threadIdx.x;

  int lo = 0, hi = N_NODES;
  while (lo < hi) { int mid = (lo + hi) >> 1; if (batch[mid] < g) lo = mid + 1; else hi = mid; }
  int s0 = lo;
  lo = 0; hi = N_NODES;
  while (lo < hi) { int mid = (lo + hi) >> 1; if (batch[mid] < g + 1) lo = mid + 1; else hi = mid; }
  int s1 = lo;

  float acc = 0.f;
  for (int n = s0; n < s1; ++n) acc += a[(size_t)n * NF + f];

  float cnt = fmaxf((float)(s1 - s0), 1.0f);
  float v = (acc / cnt) * Wfc[f];

#pragma unroll
  for (int off = 32; off > 0; off >>= 1) v += __shfl_down(v, off, 64);
  if ((f & 63) == 0) red[f >> 6] = v;
  __syncthreads();
  if (f == 0) {
    float z = red[0] + red[1];
    out[g] = 1.0f / (1.0f + expf(-z));
  }
}

extern "C" void kernel_launch(void* const* d_in, const int* in_sizes, int n_in,
                              void* d_out, int out_size, void* d_ws, size_t ws_size,
                              hipStream_t stream) {
  const float* x   = (const float*)d_in[0];
  const int*   ei  = (const int*)d_in[1];
  const int*   src = ei;               // edge_index[0]
  const int*   dst = ei + N_EDGES;     // edge_index[1]
  const int* batch = (const int*)d_in[2];
  const float* W1  = (const float*)d_in[3];
  const float* W2  = (const float*)d_in[4];
  const float* Wfc = (const float*)d_in[5];
  float* out = (float*)d_out;

  float* bufA = (float*)d_ws;                         // 6.4M floats
  float* bufB = bufA + (size_t)N_NODES * NF;          // 6.4M floats
  int* deg    = (int*)(bufB + (size_t)N_NODES * NF);  // 50000
  int* rowptr = deg + N_NODES;                        // 50001
  int* cursor = rowptr + N_NODES + 1;                 // 50001
  int* col    = cursor + N_NODES + 1;                 // 800000
  int* blocksum = col + N_EDGES;                      // SCAN_BLOCKS

  const int gemm_grid = (N_NODES + 63) / 64;            // 782
  const int edge_grid = (N_EDGES + 255) / 256;          // 3125
  const int agg_grid  = (N_NODES * 32 + 255) / 256;     // 6250

  // --- build CSR (dst -> srcs), reused by both convs ---
  hipMemsetAsync(deg, 0, N_NODES * sizeof(int), stream);
  hist_kernel<<<edge_grid, 256, 0, stream>>>(dst, deg);
  scan_stage1<<<SCAN_BLOCKS, 256, 0, stream>>>(deg, rowptr, blocksum);
  scan_stage2<<<1, 256, 0, stream>>>(blocksum);
  scan_stage3<<<SCAN_BLOCKS, 256, 0, stream>>>(rowptr, blocksum, cursor);
  fill_kernel<<<edge_grid, 256, 0, stream>>>(src, dst, cursor, col);

  // --- conv1: h = x@W1 ; aggregate ---
  gemm128<false><<<gemm_grid, 256, 0, stream>>>(x, W1, bufA, N_NODES);
  gather_agg<<<agg_grid, 256, 0, stream>>>(bufA, rowptr, col, bufB);

  // --- conv2: h = relu(bufB)@W2 ; aggregate ---
  gemm128<true><<<gemm_grid, 256, 0, stream>>>(bufB, W2, bufA, N_NODES);
  gather_agg<<<agg_grid, 256, 0, stream>>>(bufA, rowptr, col, bufB);

  // --- pool + fc + sigmoid ---
  pool_fc<<<N_GRAPHS, 128, 0, stream>>>(bufB, batch, Wfc, out);
}

// Round 4
// 216.049 us; speedup vs baseline: 3.7222x; 1.4041x over previous
//
#include <hip/hip_runtime.h>

#define N_NODES 50000
#define N_EDGES 800000
#define NF 128
#define N_GRAPHS 512
#define SCAN_BLOCKS 196   // ceil(50000/256)

union HU { ushort u; _Float16 h; };
__device__ __forceinline__ float h2f(ushort u) { HU x; x.u = u; return (float)x.h; }
__device__ __forceinline__ ushort f2h(float f) { HU x; x.h = (_Float16)f; return x.u; }

// ---------------- x (f32) -> xh (fp16), 1.6M float4 exact ---------------------
__global__ __launch_bounds__(256) void xcvt(const float* __restrict__ x,
                                            ushort* __restrict__ xh) {
  int i = blockIdx.x * 256 + threadIdx.x;
  float4 v = ((const float4*)x)[i];
  ushort4 o;
  o.x = f2h(v.x); o.y = f2h(v.y); o.z = f2h(v.z); o.w = f2h(v.w);
  ((ushort4*)xh)[i] = o;
}

// ---------------- v[f] = sum_j W2[f][j] * Wfc[j] ------------------------------
__global__ __launch_bounds__(128) void w2wfc(const float* __restrict__ W2,
                                             const float* __restrict__ Wfc,
                                             float* __restrict__ v) {
  int f = threadIdx.x;
  float s = 0.f;
  for (int j = 0; j < 128; j += 4) {
    float4 w = ((const float4*)(W2 + f * 128))[j >> 2];
    float4 c = ((const float4*)Wfc)[j >> 2];
    s += w.x * c.x + w.y * c.y + w.z * c.z + w.w * c.w;
  }
  v[f] = s;
}

// ---------------- CSR build: dst -> list of src ------------------------------
__global__ __launch_bounds__(256) void hist_kernel(const int* __restrict__ dst,
                                                   int* __restrict__ deg) {
  unsigned e = blockIdx.x * 256u + threadIdx.x;
  if (e < N_EDGES) atomicAdd(&deg[dst[e]], 1);
}

__device__ __forceinline__ int block_incl_scan_256(int v, int* warp_sums) {
  const int tid = threadIdx.x;
  const int lane = tid & 63;
  const int w = tid >> 6;
#pragma unroll
  for (int off = 1; off < 64; off <<= 1) {
    int t = __shfl_up(v, off, 64);
    if (lane >= off) v += t;
  }
  if (lane == 63) warp_sums[w] = v;
  __syncthreads();
  int ws = 0;
#pragma unroll
  for (int i = 0; i < 4; ++i) ws += (i < w) ? warp_sums[i] : 0;
  return v + ws;
}

__global__ __launch_bounds__(256) void scan_stage1(const int* __restrict__ deg,
                                                   int* __restrict__ rowptr,
                                                   int* __restrict__ blocksum) {
  __shared__ int warp_sums[4];
  int i = blockIdx.x * 256 + threadIdx.x;
  int v = (i < N_NODES) ? deg[i] : 0;
  int incl = block_incl_scan_256(v, warp_sums);
  if (i < N_NODES) rowptr[i + 1] = incl;
  if (threadIdx.x == 255) blocksum[blockIdx.x] = incl;
}

__global__ __launch_bounds__(256) void scan_stage2(int* __restrict__ blocksum) {
  __shared__ int warp_sums[4];
  int tid = threadIdx.x;
  int v = (tid < SCAN_BLOCKS) ? blocksum[tid] : 0;
  int incl = block_incl_scan_256(v, warp_sums);
  if (tid < SCAN_BLOCKS) blocksum[tid] = incl - v;
}

__global__ __launch_bounds__(256) void scan_stage3(int* __restrict__ rowptr,
                                                   const int* __restrict__ blocksum,
                                                   int* __restrict__ cursor) {
  int i = blockIdx.x * 256 + threadIdx.x;
  if (i < N_NODES) {
    int r = rowptr[i + 1] + blocksum[blockIdx.x];
    rowptr[i + 1] = r;
    cursor[i + 1] = r;
  }
  if (i == 0) { rowptr[0] = 0; cursor[0] = 0; }
}

__global__ __launch_bounds__(256) void fill_kernel(const int* __restrict__ src,
                                                   const int* __restrict__ dst,
                                                   int* __restrict__ cursor,
                                                   int* __restrict__ col) {
  unsigned e = blockIdx.x * 256u + threadIdx.x;
  if (e < N_EDGES) {
    int d = dst[e];
    int pos = atomicAdd(&cursor[d], 1);
    col[pos] = src[e];
  }
}

// ------- gather1: agg_x[n][:] = sum_{j in CSR(n)} xh[col[j]][:]  (f32 out) ---
__global__ __launch_bounds__(256) void gather_x(const ushort* __restrict__ xh,
                                                const int* __restrict__ rowptr,
                                                const int* __restrict__ col,
                                                float* __restrict__ outf) {
  unsigned gid = blockIdx.x * 256u + threadIdx.x;
  unsigned n = gid >> 5;
  unsigned q = gid & 31u;
  if (n >= N_NODES) return;
  int j0 = rowptr[n], j1 = rowptr[n + 1];
  float4 acc = float4{0.f, 0.f, 0.f, 0.f};
  int j = j0;
  for (; j + 4 <= j1; j += 4) {
    int s0 = col[j], s1 = col[j + 1], s2 = col[j + 2], s3 = col[j + 3];
    ushort4 a = ((const ushort4*)xh)[(size_t)s0 * 32 + q];
    ushort4 b = ((const ushort4*)xh)[(size_t)s1 * 32 + q];
    ushort4 c = ((const ushort4*)xh)[(size_t)s2 * 32 + q];
    ushort4 d = ((const ushort4*)xh)[(size_t)s3 * 32 + q];
    acc.x += h2f(a.x) + h2f(b.x) + h2f(c.x) + h2f(d.x);
    acc.y += h2f(a.y) + h2f(b.y) + h2f(c.y) + h2f(d.y);
    acc.z += h2f(a.z) + h2f(b.z) + h2f(c.z) + h2f(d.z);
    acc.w += h2f(a.w) + h2f(b.w) + h2f(c.w) + h2f(d.w);
  }
  for (; j < j1; ++j) {
    int s0 = col[j];
    ushort4 a = ((const ushort4*)xh)[(size_t)s0 * 32 + q];
    acc.x += h2f(a.x); acc.y += h2f(a.y); acc.z += h2f(a.z); acc.w += h2f(a.w);
  }
  ((float4*)outf)[(size_t)n * 32 + q] = acc;
}

// -------- GEMM: hA(fp16) = relu(A[M,128] @ W[128,128]) -----------------------
__global__ __launch_bounds__(256) void gemm_relu_h(const float* __restrict__ A,
                                                   const float* __restrict__ W,
                                                   ushort* __restrict__ hA, int M) {
  __shared__ float sW[32][128];
  __shared__ float sA[64][36];
  const int tid = threadIdx.x;
  const int row0 = blockIdx.x * 64;
  const int rg = tid >> 4;
  const int cg = tid & 15;

  float4 acc[4][2];
#pragma unroll
  for (int i = 0; i < 4; ++i) {
    acc[i][0] = float4{0.f, 0.f, 0.f, 0.f};
    acc[i][1] = float4{0.f, 0.f, 0.f, 0.f};
  }

  for (int kt = 0; kt < 128; kt += 32) {
#pragma unroll
    for (int i = 0; i < 4; ++i) {
      int idx = i * 256 + tid;
      int r = idx >> 5, c4 = idx & 31;
      ((float4*)&sW[r][0])[c4] = ((const float4*)W)[(kt + r) * 32 + c4];
    }
#pragma unroll
    for (int i = 0; i < 2; ++i) {
      int idx = i * 256 + tid;
      int r = idx >> 3, c4 = idx & 7;
      int gr = row0 + r;
      float4 v = float4{0.f, 0.f, 0.f, 0.f};
      if (gr < M) v = ((const float4*)A)[gr * 32 + (kt >> 2) + c4];
      *(float4*)&sA[r][c4 * 4] = v;
    }
    __syncthreads();

#pragma unroll
    for (int k = 0; k < 32; k += 4) {
      float4 a0 = *(const float4*)&sA[rg * 4 + 0][k];
      float4 a1 = *(const float4*)&sA[rg * 4 + 1][k];
      float4 a2 = *(const float4*)&sA[rg * 4 + 2][k];
      float4 a3 = *(const float4*)&sA[rg * 4 + 3][k];
      const float* ap0 = (const float*)&a0;
      const float* ap1 = (const float*)&a1;
      const float* ap2 = (const float*)&a2;
      const float* ap3 = (const float*)&a3;
#pragma unroll
      for (int kk = 0; kk < 4; ++kk) {
        float4 w0 = *(const float4*)&sW[k + kk][cg * 8];
        float4 w1 = *(const float4*)&sW[k + kk][cg * 8 + 4];
        float a0k = ap0[kk], a1k = ap1[kk], a2k = ap2[kk], a3k = ap3[kk];
#define FMA_ROW(I, AK)                                                         \
        acc[I][0].x += AK * w0.x; acc[I][0].y += AK * w0.y;                    \
        acc[I][0].z += AK * w0.z; acc[I][0].w += AK * w0.w;                    \
        acc[I][1].x += AK * w1.x; acc[I][1].y += AK * w1.y;                    \
        acc[I][1].z += AK * w1.z; acc[I][1].w += AK * w1.w;
        FMA_ROW(0, a0k)
        FMA_ROW(1, a1k)
        FMA_ROW(2, a2k)
        FMA_ROW(3, a3k)
#undef FMA_ROW
      }
    }
    __syncthreads();
  }

#pragma unroll
  for (int i = 0; i < 4; ++i) {
    int gr = row0 + rg * 4 + i;
    if (gr < M) {
      float4 a0 = acc[i][0], a1 = acc[i][1];
      a0.x = fmaxf(a0.x, 0.f); a0.y = fmaxf(a0.y, 0.f);
      a0.z = fmaxf(a0.z, 0.f); a0.w = fmaxf(a0.w, 0.f);
      a1.x = fmaxf(a1.x, 0.f); a1.y = fmaxf(a1.y, 0.f);
      a1.z = fmaxf(a1.z, 0.f); a1.w = fmaxf(a1.w, 0.f);
      uint4 o;
      o.x = (uint)f2h(a0.x) | ((uint)f2h(a0.y) << 16);
      o.y = (uint)f2h(a0.z) | ((uint)f2h(a0.w) << 16);
      o.z = (uint)f2h(a1.x) | ((uint)f2h(a1.y) << 16);
      o.w = (uint)f2h(a1.z) | ((uint)f2h(a1.w) << 16);
      ((uint4*)hA)[gr * 16 + cg] = o;
    }
  }
}

// ---- fused conv2-agg + mean-pool + FC + sigmoid (one block per graph) -------
// batch sorted => graph g's nodes [s0,s1) contiguous => its incoming messages
// are exactly col[rowptr[s0] .. rowptr[s1]). pooled_raw = sum h1[col[j]];
// z = (pooled_raw/cnt) . v  where v = W2 @ Wfc.
__global__ __launch_bounds__(512) void pool_fc_fused(const ushort* __restrict__ hA,
                                                     const int* __restrict__ rowptr,
                                                     const int* __restrict__ col,
                                                     const int* __restrict__ batch,
                                                     const float* __restrict__ v,
                                                     float* __restrict__ out) {
  __shared__ float part[16][128];
  __shared__ float reds[2];
  int g = blockIdx.x, tid = threadIdx.x;
  int q = tid & 31, eo = tid >> 5;

  int lo = 0, hi = N_NODES;
  while (lo < hi) { int m = (lo + hi) >> 1; if (batch[m] < g) lo = m + 1; else hi = m; }
  int s0 = lo;
  lo = 0; hi = N_NODES;
  while (lo < hi) { int m = (lo + hi) >> 1; if (batch[m] <= g) lo = m + 1; else hi = m; }
  int s1 = lo;

  int j0 = rowptr[s0], j1 = rowptr[s1];

  float4 acc = float4{0.f, 0.f, 0.f, 0.f};
  int j = j0 + eo;
  for (; j + 16 < j1; j += 32) {
    int sa = col[j], sb = col[j + 16];
    ushort4 ua = ((const ushort4*)hA)[(size_t)sa * 32 + q];
    ushort4 ub = ((const ushort4*)hA)[(size_t)sb * 32 + q];
    acc.x += h2f(ua.x) + h2f(ub.x);
    acc.y += h2f(ua.y) + h2f(ub.y);
    acc.z += h2f(ua.z) + h2f(ub.z);
    acc.w += h2f(ua.w) + h2f(ub.w);
  }
  if (j < j1) {
    int sa = col[j];
    ushort4 ua = ((const ushort4*)hA)[(size_t)sa * 32 + q];
    acc.x += h2f(ua.x); acc.y += h2f(ua.y); acc.z += h2f(ua.z); acc.w += h2f(ua.w);
  }
  *(float4*)&part[eo][q * 4] = acc;
  __syncthreads();

  float z = 0.f;
  if (tid < 128) {
    float s = 0.f;
#pragma unroll
    for (int i = 0; i < 16; ++i) s += part[i][tid];
    float cnt = fmaxf((float)(s1 - s0), 1.0f);
    z = (s / cnt) * v[tid];
  }
#pragma unroll
  for (int off = 32; off > 0; off >>= 1) z += __shfl_down(z, off, 64);
  if (tid == 0) reds[0] = z;
  if (tid == 64) reds[1] = z;
  __syncthreads();
  if (tid == 0) {
    float zz = reds[0] + reds[1];
    out[g] = 1.0f / (1.0f + expf(-zz));
  }
}

extern "C" void kernel_launch(void* const* d_in, const int* in_sizes, int n_in,
                              void* d_out, int out_size, void* d_ws, size_t ws_size,
                              hipStream_t stream) {
  const float* x   = (const float*)d_in[0];
  const int*   ei  = (const int*)d_in[1];
  const int*   src = ei;               // edge_index[0]
  const int*   dst = ei + N_EDGES;     // edge_index[1]
  const int* batch = (const int*)d_in[2];
  const float* W1  = (const float*)d_in[3];
  const float* W2  = (const float*)d_in[4];
  const float* Wfc = (const float*)d_in[5];
  float* out = (float*)d_out;

  float*  bufA = (float*)d_ws;                          // 6.4M f32 (agg_x)
  ushort* xh   = (ushort*)(bufA + (size_t)N_NODES * NF);   // 6.4M fp16
  ushort* hA   = xh + (size_t)N_NODES * NF;                // 6.4M fp16
  int* deg     = (int*)(hA + (size_t)N_NODES * NF);
  int* rowptr  = deg + N_NODES;          // N_NODES+1
  int* cursor  = rowptr + N_NODES + 1;   // N_NODES+1
  int* col     = cursor + N_NODES + 1;   // N_EDGES
  int* blocksum = col + N_EDGES;         // SCAN_BLOCKS
  float* v     = (float*)(blocksum + SCAN_BLOCKS + 4); // 128

  const int gemm_grid = (N_NODES + 63) / 64;            // 782
  const int edge_grid = (N_EDGES + 255) / 256;          // 3125
  const int agg_grid  = (N_NODES * 32 + 255) / 256;     // 6250
  const int cvt_grid  = (N_NODES * NF / 4) / 256;       // 6250 exact

  // --- build CSR (dst -> srcs) ---
  hipMemsetAsync(deg, 0, N_NODES * sizeof(int), stream);
  hist_kernel<<<edge_grid, 256, 0, stream>>>(dst, deg);
  scan_stage1<<<SCAN_BLOCKS, 256, 0, stream>>>(deg, rowptr, blocksum);
  scan_stage2<<<1, 256, 0, stream>>>(blocksum);
  scan_stage3<<<SCAN_BLOCKS, 256, 0, stream>>>(rowptr, blocksum, cursor);
  fill_kernel<<<edge_grid, 256, 0, stream>>>(src, dst, cursor, col);

  // --- precompute fp16 x and v = W2@Wfc ---
  xcvt<<<cvt_grid, 256, 0, stream>>>(x, xh);
  w2wfc<<<1, 128, 0, stream>>>(W2, Wfc, v);

  // --- conv1: agg_x = gather(x); h1 = relu(agg_x @ W1) (fp16) ---
  gather_x<<<agg_grid, 256, 0, stream>>>(xh, rowptr, col, bufA);
  gemm_relu_h<<<gemm_grid, 256, 0, stream>>>(bufA, W1, hA, N_NODES);

  // --- conv2 + pool + fc + sigmoid, fused per graph ---
  pool_fc_fused<<<N_GRAPHS, 512, 0, stream>>>(hA, rowptr, col, batch, v, out);
}